// Round 2
// baseline (618.546 us; speedup 1.0000x reference)
//
#include <hip/hip_runtime.h>
#include <math.h>

// VectorCapsules fused kernel — one workgroup per batch element.
// Phases: (0) stage input/W1/b1/bp to LDS, (1) stride-4 conv -> xs (LDS),
// (2) pc einsum + squash + caps matvec -> u (LDS), (3) 4 routing rounds.
// Routing trick: b_batch[i,o] = b_route[i,o] + u[i,o]*V[o], V = running sum of v.

#define NTH    512
#define NWAVES 8
#define IC     6272      // 32*14*14 capsules
#define NCLS   5

__global__ __launch_bounds__(NTH, 1)
void caps_fused(const float* __restrict__ inp,
                const float* __restrict__ W1,
                const float* __restrict__ b1,
                const float* __restrict__ Wp,
                const float* __restrict__ bp,
                const float* __restrict__ capsW,
                const float* __restrict__ broute,
                float* __restrict__ out)
{
    extern __shared__ float lds[];
    float* s_xs  = lds;            // 6272  : xs[c][hw], 32 x 196
    float* s_W1  = s_xs + 6272;    // 800
    float* s_b1  = s_W1 + 800;     // 32
    float* s_bp  = s_b1 + 32;      // 448
    float* s_red = s_bp + 448;     // 40 (8 waves x 5)
    float* s_v   = s_red + 40;     // 8 (5 used)
    float* s_u   = s_v + 8;        // 31360 : u[n][5]  (aliases s_in[3481])
    float* s_in  = s_u;            // 3481 during phases 0/1 only

    const int b    = blockIdx.x;
    const int tid  = threadIdx.x;
    const int lane = tid & 63;
    const int wv   = tid >> 6;

    // ---------------- Phase 0: stage ----------------
    const float* inb = inp + (size_t)b * (59 * 59);
    for (int i = tid; i < 59 * 59; i += NTH) s_in[i] = inb[i];
    for (int i = tid; i < 800;     i += NTH) s_W1[i] = W1[i];
    if (tid < 32) s_b1[tid] = b1[tid];
    for (int i = tid; i < 448;     i += NTH) s_bp[i] = bp[i];
    __syncthreads();

    // ---------------- Phase 1: conv (only ::2,::2 outputs => stride 4) ----
    // xs[c][h*14+w] = relu(b1[c] + sum_{kh,kw} in[4h+kh][4w+kw]*W1[c][kh][kw])
    for (int n = tid; n < IC; n += NTH) {
        const int c  = n / 196;
        const int hw = n - c * 196;
        const int h  = hw / 14;
        const int w  = hw - h * 14;
        const float* ip = s_in + (4 * h) * 59 + 4 * w;
        const float* wk = s_W1 + c * 25;
        float acc = s_b1[c];
        #pragma unroll
        for (int kh = 0; kh < 5; ++kh)
            #pragma unroll
            for (int kw = 0; kw < 5; ++kw)
                acc = fmaf(ip[kh * 59 + kw], wk[kh * 5 + kw], acc);
        s_xs[n] = fmaxf(acc, 0.0f);
    }
    __syncthreads();
    // s_in region is dead from here; s_u may overwrite it.

    // ---------------- Phase 2: pc -> squash -> u ----------------
    // wave wv handles g in {wv, wv+8, wv+16, wv+24}; lanes+rounds cover hw.
    for (int gi = 0; gi < 4; ++gi) {
        const int g = wv + gi * NWAVES;
        float pc0[14], pc1[14], pc2[14], pc3[14];
        #pragma unroll
        for (int i = 0; i < 14; ++i) { pc0[i] = 0.f; pc1[i] = 0.f; pc2[i] = 0.f; pc3[i] = 0.f; }
        const float* wpg = Wp + (size_t)g * (14 * 32);
        for (int c = 0; c < 32; ++c) {
            const float* xc = s_xs + c * 196;
            const float x0 = xc[lane];
            const float x1 = xc[64 + lane];
            const float x2 = xc[128 + lane];
            const float x3 = xc[192 + (lane & 3)];   // only lanes<4 are real (hw<196)
            #pragma unroll
            for (int i = 0; i < 14; ++i) {
                const float w = wpg[i * 32 + c];     // wave-uniform -> L1 broadcast
                pc0[i] = fmaf(w, x0, pc0[i]);
                pc1[i] = fmaf(w, x1, pc1[i]);
                pc2[i] = fmaf(w, x2, pc2[i]);
                pc3[i] = fmaf(w, x3, pc3[i]);
            }
        }
        auto emit = [&](float* pc, int r) {
            const int hw = r * 64 + lane;
            if (hw < 196) {
                const int n = g * 196 + hw;
                float sq = 0.f;
                #pragma unroll
                for (int i = 0; i < 14; ++i) {
                    pc[i] += s_bp[g * 14 + i];
                    sq = fmaf(pc[i], pc[i], sq);
                }
                const float scale = sq / (1.0f + sq) / sqrtf(sq);
                float uo[5] = {0.f, 0.f, 0.f, 0.f, 0.f};
                const float* cw = capsW + (size_t)n * 70;
                #pragma unroll
                for (int i = 0; i < 14; ++i) {
                    const float p = pc[i] * scale;
                    #pragma unroll
                    for (int o = 0; o < 5; ++o)
                        uo[o] = fmaf(p, cw[i * 5 + o], uo[o]);
                }
                #pragma unroll
                for (int o = 0; o < 5; ++o) s_u[n * 5 + o] = uo[o];
            }
        };
        emit(pc0, 0); emit(pc1, 1); emit(pc2, 2); emit(pc3, 3);
    }
    __syncthreads();

    // ---------------- Phase 3: routing (initial + 3 iters) ----------------
    float V[5] = {0.f, 0.f, 0.f, 0.f, 0.f};
    for (int it = 0; it < 4; ++it) {
        float sacc[5] = {0.f, 0.f, 0.f, 0.f, 0.f};
        for (int n = tid; n < IC; n += NTH) {
            const float* br = broute + (size_t)n * 5;
            float uu[5], l[5];
            #pragma unroll
            for (int o = 0; o < 5; ++o) {
                uu[o] = s_u[n * 5 + o];
                l[o]  = fmaf(uu[o], V[o], br[o]);
            }
            const float m = fmaxf(fmaxf(fmaxf(l[0], l[1]), fmaxf(l[2], l[3])), l[4]);
            float e[5], es = 0.f;
            #pragma unroll
            for (int o = 0; o < 5; ++o) { e[o] = __expf(l[o] - m); es += e[o]; }
            const float inv = 1.0f / es;
            #pragma unroll
            for (int o = 0; o < 5; ++o)
                sacc[o] = fmaf(uu[o], e[o] * inv, sacc[o]);
        }
        // wave reduce then cross-wave via LDS
        #pragma unroll
        for (int off = 32; off > 0; off >>= 1)
            #pragma unroll
            for (int o = 0; o < 5; ++o)
                sacc[o] += __shfl_down(sacc[o], off);
        if (lane == 0) {
            #pragma unroll
            for (int o = 0; o < 5; ++o) s_red[wv * 5 + o] = sacc[o];
        }
        __syncthreads();
        if (tid == 0) {
            #pragma unroll
            for (int o = 0; o < 5; ++o) {
                float s = 0.f;
                for (int w2 = 0; w2 < NWAVES; ++w2) s += s_red[w2 * 5 + o];
                s_v[o] = s * fabsf(s) / (1.0f + s * s);   // squash, OUT_DIM=1
            }
        }
        __syncthreads();
        #pragma unroll
        for (int o = 0; o < 5; ++o) V[o] += s_v[o];
    }

    if (tid < NCLS) out[b * NCLS + tid] = fabsf(s_v[tid]);
}

extern "C" void kernel_launch(void* const* d_in, const int* in_sizes, int n_in,
                              void* d_out, int out_size, void* d_ws, size_t ws_size,
                              hipStream_t stream)
{
    const float* inp   = (const float*)d_in[0];
    // d_in[1] = r (python scalar, unused by reference)
    const float* W1    = (const float*)d_in[2];
    const float* b1    = (const float*)d_in[3];
    const float* Wp    = (const float*)d_in[4];
    const float* bp    = (const float*)d_in[5];
    const float* capsW = (const float*)d_in[6];
    const float* brt   = (const float*)d_in[7];
    float* out = (float*)d_out;

    const int B = in_sizes[0] / (59 * 59);   // 1024
    const size_t lds_bytes = (size_t)(6272 + 800 + 32 + 448 + 40 + 8 + 31360) * sizeof(float);
    // allow >64KB dynamic LDS (gfx950 has 160KB/CU); harmless if already set
    (void)hipFuncSetAttribute((const void*)caps_fused,
                              hipFuncAttributeMaxDynamicSharedMemorySize,
                              (int)lds_bytes);
    caps_fused<<<B, NTH, lds_bytes, stream>>>(inp, W1, b1, Wp, bp, capsW, brt, out);
}